// Round 5
// baseline (480.454 us; speedup 1.0000x reference)
//
#include <hip/hip_runtime.h>

// GatedMetaFusion R5.
//   prep: W^T bf16 x8; A2 = res[0:M]@g2A + g2b1 (b1 folded), M2 = meta@g2B
//   CSR over dst (M buckets; dst ∈ [0,M)), fill writes per-edge records
//     rec = {evec0, evec1, evec2, bitcast(src)}  (coalesced tile reads later)
//   UNION kernel (interleaved grid, 5 edge : 1 gate1):
//     edge path (node split-4, 2 syncs/tile):
//       h = relu(A2[n] + M2[src] + evec.Wc); g = h@g2W2 (MFMA)
//       psum += (g+b2)*meta[src]; shfl-reduce; atomicAdd SUM[n]
//     FN-A path (gate1): h1 = relu(res@g1A + meta[sec]@g1B + b1 - pe.Wc)
//       g = h1@g1W2; FP = res + (g+b2)*meta[sec]   (fp32, staging layout)
//   FN-B: fused = FP + SUM/cnt; out = relu(fused@fW1+fb1)@fW2+fb2  (2 syncs)
//
// MFMA 16x16x32 bf16 layouts (verified): A[m=lane&15][k=quad*8+j],
// B from W^T row-major 16B/lane, C/D: col=lane&15, row=quad*4+reg.

typedef short bf16x8 __attribute__((ext_vector_type(8)));
typedef float f32x4  __attribute__((ext_vector_type(4)));

#define XS_PAD 136   // bf16 row stride (272B, 16B-aligned)
#define S_SPLIT 4

__device__ __forceinline__ unsigned short f2bf(float f){
  union { float f; unsigned u; } v; v.f = f;
  return (unsigned short)((v.u + 0x7FFFu + ((v.u >> 16) & 1u)) >> 16);
}
__device__ __forceinline__ unsigned pack2(float a, float b){
  return (unsigned)f2bf(a) | ((unsigned)f2bf(b) << 16);
}
__device__ __forceinline__ float bf2f(unsigned short u){
  union { unsigned u; float f; } v; v.u = ((unsigned)u) << 16; return v.f;
}

__device__ __forceinline__ void mfma_layer(const unsigned short* Xs,
                                           const bf16x8 (&B)[2][4],
                                           int lane, f32x4 (&acc)[4][2]) {
  const int lcol = lane & 15, quad = lane >> 4;
  #pragma unroll
  for (int rg = 0; rg < 4; ++rg) {
    bf16x8 A[4];
    const unsigned short* ab = Xs + (rg*16 + lcol)*XS_PAD + quad*8;
    #pragma unroll
    for (int kk = 0; kk < 4; ++kk) A[kk] = *(const bf16x8*)(ab + kk*32);
    #pragma unroll
    for (int ctl = 0; ctl < 2; ++ctl)
      #pragma unroll
      for (int kk = 0; kk < 4; ++kk)
        acc[rg][ctl] = __builtin_amdgcn_mfma_f32_16x16x32_bf16(
            A[kk], B[ctl][kk], acc[rg][ctl], 0, 0, 0);
  }
}

__device__ __forceinline__ void load_bfrags(const unsigned short* __restrict__ Wt,
                                            int wave, int lane, bf16x8 (&B)[2][4]) {
  const int lcol = lane & 15, quad = lane >> 4;
  #pragma unroll
  for (int ctl = 0; ctl < 2; ++ctl) {
    int col = (wave*2 + ctl)*16 + lcol;
    #pragma unroll
    for (int kk = 0; kk < 4; ++kk)
      B[ctl][kk] = *(const bf16x8*)(Wt + (size_t)col*128 + kk*32 + quad*8);
  }
}

__device__ __forceinline__ void zero_acc(f32x4 (&acc)[4][2]) {
  #pragma unroll
  for (int rg = 0; rg < 4; ++rg)
    #pragma unroll
    for (int ctl = 0; ctl < 2; ++ctl) {
      acc[rg][ctl][0]=0.f; acc[rg][ctl][1]=0.f;
      acc[rg][ctl][2]=0.f; acc[rg][ctl][3]=0.f;
    }
}

// ---------------- 8-slab W^T bf16 prep ----------------
struct WPtrs { const float* s[8]; };
__global__ __launch_bounds__(256) void transpose_w8(WPtrs p,
                                                    unsigned short* __restrict__ dstbase) {
  int slab = blockIdx.x >> 4, blk = blockIdx.x & 15;
  const float* W = p.s[slab];
  unsigned short* Wt = dstbase + (size_t)slab*16384;
  int c  = blk*8 + (threadIdx.x >> 5);
  int k0 = (threadIdx.x & 31) * 4;
  unsigned short o[4];
  #pragma unroll
  for (int j = 0; j < 4; ++j) o[j] = f2bf(W[(size_t)(k0 + j)*128 + c]);
  *(uint2*)(Wt + (size_t)c*128 + k0) =
      make_uint2((unsigned)o[0] | ((unsigned)o[1] << 16),
                 (unsigned)o[2] | ((unsigned)o[3] << 16));
}

// ------- prep: A2 = res[0:M]@g2A + g2b1 (y=0), M2 = meta@g2B (y=1) -------
__global__ __launch_bounds__(256) void prep_mfma(const float* __restrict__ res,
                                                 const float* __restrict__ meta,
                                                 const unsigned short* __restrict__ WAt,
                                                 const unsigned short* __restrict__ WBt,
                                                 const float* __restrict__ g2b1,
                                                 float* __restrict__ A2,
                                                 float* __restrict__ M2, int mrows) {
  __shared__ __align__(16) unsigned short Xs[64*XS_PAD];
  const int t = threadIdx.x, lane = t & 63, wave = t >> 6;
  const int quad = lane >> 4, lcol = lane & 15;
  const int tile0 = blockIdx.x * 64;
  const float* X = blockIdx.y ? meta : res;
  const unsigned short* Wt = blockIdx.y ? WBt : WAt;
  float* Y = blockIdx.y ? M2 : A2;
  bf16x8 B[2][4];
  load_bfrags(Wt, wave, lane, B);
  #pragma unroll
  for (int i = 0; i < 8; ++i) {
    int f = t + i*256, row = f >> 5, c4 = f & 31;
    int gr = tile0 + row;
    float4 v = make_float4(0.f,0.f,0.f,0.f);
    if (gr < mrows) v = *(const float4*)(X + (size_t)gr*128 + c4*4);
    *(uint2*)(Xs + row*XS_PAD + c4*4) = make_uint2(pack2(v.x,v.y), pack2(v.z,v.w));
  }
  __syncthreads();
  f32x4 acc[4][2]; zero_acc(acc);
  mfma_layer(Xs, B, lane, acc);
  #pragma unroll
  for (int rg = 0; rg < 4; ++rg)
    #pragma unroll
    for (int ctl = 0; ctl < 2; ++ctl) {
      int col = (wave*2 + ctl)*16 + lcol;
      float bias = blockIdx.y ? 0.f : g2b1[col];
      #pragma unroll
      for (int reg = 0; reg < 4; ++reg) {
        int gr = tile0 + rg*16 + quad*4 + reg;
        if (gr < mrows) Y[(size_t)gr*128 + col] = acc[rg][ctl][reg] + bias;
      }
    }
}

// ---------------- CSR build (M buckets) ----------------
__global__ void hist_kernel(const int* __restrict__ dst, int* __restrict__ counts, int E){
  int e = blockIdx.x*256 + threadIdx.x;
  if (e < E) atomicAdd(&counts[dst[e]], 1);
}
__global__ void scan1(const int* __restrict__ counts, int* __restrict__ exoff,
                      int* __restrict__ blocksum, int N){
  __shared__ int s[256];
  int t = threadIdx.x, gid = blockIdx.x*256 + t;
  int v = (gid < N) ? counts[gid] : 0;
  s[t] = v; __syncthreads();
  for (int off = 1; off < 256; off <<= 1){
    int x = (t >= off) ? s[t-off] : 0; __syncthreads();
    s[t] += x; __syncthreads();
  }
  if (gid < N) exoff[gid] = s[t] - v;
  if (t == 255) blocksum[blockIdx.x] = s[255];
}
__global__ void scan2(int* __restrict__ blocksum, int nb){
  __shared__ int s[512];
  int t = threadIdx.x;
  int v = (t < nb) ? blocksum[t] : 0;
  s[t] = v; __syncthreads();
  for (int off = 1; off < 512; off <<= 1){
    int x = (t >= off) ? s[t-off] : 0; __syncthreads();
    s[t] += x; __syncthreads();
  }
  if (t < nb) blocksum[t] = s[t] - v;
}
__global__ void scan3(int* __restrict__ exoff, const int* __restrict__ blockbase,
                      int* __restrict__ cursor, int N){
  int gid = blockIdx.x*256 + threadIdx.x;
  if (gid < N){ int v = exoff[gid] + blockbase[gid >> 8]; exoff[gid] = v; cursor[gid] = v; }
}
// fill: per-edge record {evec.xyz, bitcast(src)} at CSR position
__global__ void fill_kernel(const int* __restrict__ src, const int* __restrict__ dst,
                            const float* __restrict__ evec, int* __restrict__ cursor,
                            float4* __restrict__ recs, int E){
  int e = blockIdx.x*256 + threadIdx.x;
  if (e < E){
    int p = atomicAdd(&cursor[dst[e]], 1);
    recs[p] = make_float4(evec[(size_t)e*3], evec[(size_t)e*3+1],
                          evec[(size_t)e*3+2], __int_as_float(src[e]));
  }
}

// ---------------- edge path (device fn; uses Xh = 64*XS_PAD shorts) ----------------
__device__ __forceinline__ void edge_path(
    int bid, const float* __restrict__ A2b, const float* __restrict__ M2,
    const float* __restrict__ meta, const float4* __restrict__ recs,
    const int* __restrict__ row_start, const int* __restrict__ counts,
    const float* __restrict__ g2W1full, const unsigned short* __restrict__ W2t,
    const float* __restrict__ b2, float* __restrict__ SUM,
    unsigned short* Xh) {
  const int n = bid / S_SPLIT, k = bid % S_SPLIT;
  const int count = counts[n];
  const int per = (count + S_SPLIT - 1) / S_SPLIT;
  const int lo = k * per;
  int hi = lo + per; if (hi > count) hi = count;
  const int cnt = hi - lo;
  if (cnt <= 0) return;
  const int rs = row_start[n] + lo;

  const int t = threadIdx.x, lane = t & 63, wave = t >> 6;
  const int quad = lane >> 4, lcol = lane & 15;
  const int c0 = (t & 31) * 4, rbase = t >> 5;

  bf16x8 BW2[2][4];
  load_bfrags(W2t, wave, lane, BW2);
  float4 base = *(const float4*)(A2b + (size_t)n*128 + c0);   // b1 pre-folded
  float4 w0 = *(const float4*)(g2W1full + 256*128 + c0);
  float4 w1 = *(const float4*)(g2W1full + 257*128 + c0);
  float4 w2 = *(const float4*)(g2W1full + 258*128 + c0);
  const int colA = wave*32 + lcol, colB = colA + 16;
  const float b2A = b2[colA], b2B = b2[colB];
  float psA = 0.f, psB = 0.f;

  for (int t0 = 0; t0 < cnt; t0 += 64) {
    if (t0) __syncthreads();               // prev tile fully consumed
    #pragma unroll
    for (int i = 0; i < 8; ++i) {          // h = relu(base + M2[src] + evec.Wc)
      int row = rbase + 8*i;
      float4 h = make_float4(0.f,0.f,0.f,0.f);
      if (t0 + row < cnt) {
        float4 rec = recs[rs + t0 + row];  // broadcast per 32 lanes
        int s = __float_as_int(rec.w);
        float4 m = *(const float4*)(M2 + (size_t)s*128 + c0);
        h.x = fmaxf(base.x + m.x + rec.x*w0.x + rec.y*w1.x + rec.z*w2.x, 0.f);
        h.y = fmaxf(base.y + m.y + rec.x*w0.y + rec.y*w1.y + rec.z*w2.y, 0.f);
        h.z = fmaxf(base.z + m.z + rec.x*w0.z + rec.y*w1.z + rec.z*w2.z, 0.f);
        h.w = fmaxf(base.w + m.w + rec.x*w0.w + rec.y*w1.w + rec.z*w2.w, 0.f);
      }
      *(uint2*)(Xh + row*XS_PAD + c0) = make_uint2(pack2(h.x,h.y), pack2(h.z,h.w));
    }
    __syncthreads();
    f32x4 acc[4][2]; zero_acc(acc);
    mfma_layer(Xh, BW2, lane, acc);        // g = h @ g2W2
    #pragma unroll
    for (int rg = 0; rg < 4; ++rg)         // psum += (g+b2)*meta[src]
      #pragma unroll
      for (int reg = 0; reg < 4; ++reg) {
        int rl = rg*16 + quad*4 + reg;
        if (t0 + rl < cnt) {
          int s = __float_as_int(recs[rs + t0 + rl].w);
          psA += (acc[rg][0][reg] + b2A) * meta[(size_t)s*128 + colA];
          psB += (acc[rg][1][reg] + b2B) * meta[(size_t)s*128 + colB];
        }
      }
  }
  psA += __shfl_xor(psA, 16, 64); psA += __shfl_xor(psA, 32, 64);
  psB += __shfl_xor(psB, 16, 64); psB += __shfl_xor(psB, 32, 64);
  if (quad == 0) {
    atomicAdd(&SUM[(size_t)n*128 + colA], psA);
    atomicAdd(&SUM[(size_t)n*128 + colB], psB);
  }
}

// ---------------- FN-A path: gate1 -> FP (device fn; uses Xa, Xm) ----------------
__device__ __forceinline__ void fna_path(
    int bid, const float* __restrict__ res, const float* __restrict__ meta,
    const int* __restrict__ sec_ids, const float* __restrict__ pe,
    const float* __restrict__ g1W1full,
    const unsigned short* __restrict__ g1At, const unsigned short* __restrict__ g1Bt,
    const unsigned short* __restrict__ g1W2t,
    const float* __restrict__ g1b1, const float* __restrict__ g1b2,
    float* __restrict__ FP, int rows,
    unsigned short* Xa, unsigned short* Xm) {
  const int t = threadIdx.x, lane = t & 63, wave = t >> 6;
  const int quad = lane >> 4, lcol = lane & 15;
  const int tile0 = bid * 64;
  const int c0 = (t & 31) * 4, rbase = t >> 5;
  const int colA = wave*32 + lcol, colB = colA + 16;
  const float b1A = g1b1[colA],  b1B = g1b1[colB];
  const float b2A = g1b2[colA],  b2B = g1b2[colB];
  const float wA0 = g1W1full[256*128+colA], wA1 = g1W1full[257*128+colA],
              wA2 = g1W1full[258*128+colA];
  const float wB0 = g1W1full[256*128+colB], wB1 = g1W1full[257*128+colB],
              wB2 = g1W1full[258*128+colB];
  bf16x8 BA[2][4], BB[2][4];
  load_bfrags(g1At, wave, lane, BA);
  load_bfrags(g1Bt, wave, lane, BB);

  #pragma unroll
  for (int i = 0; i < 8; ++i) {                           // stage res, meta[sec]
    int row = rbase + 8*i;
    int gr = tile0 + row;
    float4 rv = make_float4(0.f,0.f,0.f,0.f);
    float4 mv = make_float4(0.f,0.f,0.f,0.f);
    if (gr < rows) {
      int sid = sec_ids[gr];                              // broadcast per 32 lanes
      rv = *(const float4*)(res  + (size_t)gr*128 + c0);
      mv = *(const float4*)(meta + (size_t)sid*128 + c0);
    }
    *(uint2*)(Xa + row*XS_PAD + c0) = make_uint2(pack2(rv.x,rv.y), pack2(rv.z,rv.w));
    *(uint2*)(Xm + row*XS_PAD + c0) = make_uint2(pack2(mv.x,mv.y), pack2(mv.z,mv.w));
  }
  __syncthreads();                                        // 1
  f32x4 acc[4][2]; zero_acc(acc);
  mfma_layer(Xa, BA, lane, acc);                          // res @ g1A
  mfma_layer(Xm, BB, lane, acc);                          // + meta[sec] @ g1B
  __syncthreads();                                        // 2: Xa reads done
  #pragma unroll
  for (int rg = 0; rg < 4; ++rg)                          // h1 -> Xa
    #pragma unroll
    for (int reg = 0; reg < 4; ++reg) {
      int row = rg*16 + quad*4 + reg;
      int gr = tile0 + row;
      float p0=0.f, p1=0.f, p2=0.f;
      if (gr < rows) {
        p0 = pe[(size_t)gr*3]; p1 = pe[(size_t)gr*3+1]; p2 = pe[(size_t)gr*3+2];
      }
      float vA = acc[rg][0][reg] + b1A - p0*wA0 - p1*wA1 - p2*wA2;
      float vB = acc[rg][1][reg] + b1B - p0*wB0 - p1*wB1 - p2*wB2;
      Xa[row*XS_PAD + colA] = f2bf(fmaxf(vA, 0.f));
      Xa[row*XS_PAD + colB] = f2bf(fmaxf(vB, 0.f));
    }
  __syncthreads();                                        // 3
  bf16x8 B2g[2][4]; load_bfrags(g1W2t, wave, lane, B2g);
  zero_acc(acc);
  mfma_layer(Xa, B2g, lane, acc);                         // g = h1 @ g1W2
  __syncthreads();                                        // 4: Xa reads done
  #pragma unroll
  for (int rg = 0; rg < 4; ++rg)                          // g+b2 -> Xa (bf16)
    #pragma unroll
    for (int reg = 0; reg < 4; ++reg) {
      int row = rg*16 + quad*4 + reg;
      Xa[row*XS_PAD + colA] = f2bf(acc[rg][0][reg] + b2A);
      Xa[row*XS_PAD + colB] = f2bf(acc[rg][1][reg] + b2B);
    }
  __syncthreads();                                        // 5
  #pragma unroll
  for (int i = 0; i < 8; ++i) {                           // FP = res + g*meta
    int row = rbase + 8*i;
    int gr = tile0 + row;
    if (gr < rows) {
      float4 rv = *(const float4*)(res + (size_t)gr*128 + c0);
      uint2 gu = *(const uint2*)(Xa + row*XS_PAD + c0);
      uint2 mu = *(const uint2*)(Xm + row*XS_PAD + c0);
      float g0 = bf2f((unsigned short)(gu.x & 0xFFFF)), g1 = bf2f((unsigned short)(gu.x >> 16));
      float g2 = bf2f((unsigned short)(gu.y & 0xFFFF)), g3 = bf2f((unsigned short)(gu.y >> 16));
      float m0 = bf2f((unsigned short)(mu.x & 0xFFFF)), m1 = bf2f((unsigned short)(mu.x >> 16));
      float m2 = bf2f((unsigned short)(mu.y & 0xFFFF)), m3 = bf2f((unsigned short)(mu.y >> 16));
      *(float4*)(FP + (size_t)gr*128 + c0) =
          make_float4(rv.x + g0*m0, rv.y + g1*m1, rv.z + g2*m2, rv.w + g3*m3);
    }
  }
}

// ---------------- UNION kernel: interleave edge (5) : FN-A (1) ----------------
__global__ __launch_bounds__(256) void union_kernel(
    const float* __restrict__ A2b, const float* __restrict__ M2,
    const float* __restrict__ meta, const float4* __restrict__ recs,
    const int* __restrict__ row_start, const int* __restrict__ counts,
    const float* __restrict__ g2W1full, const unsigned short* __restrict__ g2W2t,
    const float* __restrict__ g2b2, float* __restrict__ SUM, int nEdge,
    const float* __restrict__ res, const int* __restrict__ sec_ids,
    const float* __restrict__ pe, const float* __restrict__ g1W1full,
    const unsigned short* __restrict__ g1At, const unsigned short* __restrict__ g1Bt,
    const unsigned short* __restrict__ g1W2t,
    const float* __restrict__ g1b1, const float* __restrict__ g1b2,
    float* __restrict__ FP, int rows, int nFNA) {
  __shared__ __align__(16) unsigned short Xa[64*XS_PAD];
  __shared__ __align__(16) unsigned short Xm[64*XS_PAD];
  int f = blockIdx.x / 6, r = blockIdx.x % 6;
  if (r == 5) {
    if (f < nFNA)
      fna_path(f, res, meta, sec_ids, pe, g1W1full, g1At, g1Bt, g1W2t,
               g1b1, g1b2, FP, rows, Xa, Xm);
  } else {
    int eid = f*5 + r;
    if (eid < nEdge)
      edge_path(eid, A2b, M2, meta, recs, row_start, counts,
                g2W1full, g2W2t, g2b2, SUM, Xa);
  }
}

// ---------------- FN-B: fused build + final 2-layer MLP (2 syncs) ----------------
__global__ __launch_bounds__(256) void fnb_kernel(
    const float* __restrict__ FP, const float* __restrict__ SUM,
    const int* __restrict__ counts, int msize,
    const unsigned short* __restrict__ fW1t, const float* __restrict__ fb1v,
    const unsigned short* __restrict__ fW2t, const float* __restrict__ fb2v,
    float* __restrict__ out, int rows) {
  __shared__ __align__(16) unsigned short Xa[64*XS_PAD];
  __shared__ __align__(16) unsigned short Xm[64*XS_PAD];
  const int t = threadIdx.x, lane = t & 63, wave = t >> 6;
  const int quad = lane >> 4, lcol = lane & 15;
  const int tile0 = blockIdx.x * 64;
  const int c0 = (t & 31) * 4, rbase = t >> 5;
  const int colA = wave*32 + lcol, colB = colA + 16;
  const float fb1A = fb1v[colA], fb1B = fb1v[colB];
  const float fb2A = fb2v[colA], fb2B = fb2v[colB];
  bf16x8 BF1[2][4], BF2[2][4];
  load_bfrags(fW1t, wave, lane, BF1);
  load_bfrags(fW2t, wave, lane, BF2);

  #pragma unroll
  for (int i = 0; i < 8; ++i) {                 // fused = FP + SUM/cnt -> Xm
    int row = rbase + 8*i;
    int gr = tile0 + row;
    float4 v = make_float4(0.f,0.f,0.f,0.f);
    if (gr < rows) {
      v = *(const float4*)(FP + (size_t)gr*128 + c0);
      if (gr < msize) {
        int c = counts[gr];                     // broadcast per 32 lanes
        if (c > 0) {
          float iv = 1.f / (float)c;
          float4 s = *(const float4*)(SUM + (size_t)gr*128 + c0);
          v.x += s.x*iv; v.y += s.y*iv; v.z += s.z*iv; v.w += s.w*iv;
        }
      }
    }
    *(uint2*)(Xm + row*XS_PAD + c0) = make_uint2(pack2(v.x,v.y), pack2(v.z,v.w));
  }
  __syncthreads();                              // 1
  f32x4 acc[4][2]; zero_acc(acc);
  mfma_layer(Xm, BF1, lane, acc);               // fused @ fW1
  #pragma unroll
  for (int rg = 0; rg < 4; ++rg)                // h2 -> Xa (fresh buffer, no sync)
    #pragma unroll
    for (int reg = 0; reg < 4; ++reg) {
      int row = rg*16 + quad*4 + reg;
      Xa[row*XS_PAD + colA] = f2bf(fmaxf(acc[rg][0][reg] + fb1A, 0.f));
      Xa[row*XS_PAD + colB] = f2bf(fmaxf(acc[rg][1][reg] + fb1B, 0.f));
    }
  __syncthreads();                              // 2
  zero_acc(acc);
  mfma_layer(Xa, BF2, lane, acc);               // out = h2 @ fW2
  #pragma unroll
  for (int rg = 0; rg < 4; ++rg)                // direct C-layout store
    #pragma unroll
    for (int reg = 0; reg < 4; ++reg) {
      int gr = tile0 + rg*16 + quad*4 + reg;
      if (gr < rows) {
        out[(size_t)gr*128 + colA] = acc[rg][0][reg] + fb2A;
        out[(size_t)gr*128 + colB] = acc[rg][1][reg] + fb2B;
      }
    }
}

extern "C" void kernel_launch(void* const* d_in, const int* in_sizes, int n_in,
                              void* d_out, int out_size, void* d_ws, size_t ws_size,
                              hipStream_t stream) {
  const float* res     = (const float*)d_in[0];
  const float* meta    = (const float*)d_in[1];
  const int*   sec_ids = (const int*)  d_in[2];
  const float* pe      = (const float*)d_in[3];
  const int*   edge    = (const int*)  d_in[4];
  const float* evec    = (const float*)d_in[5];
  const float* g1W1 = (const float*)d_in[6];
  const float* g1b1 = (const float*)d_in[7];
  const float* g1W2 = (const float*)d_in[8];
  const float* g1b2 = (const float*)d_in[9];
  const float* g2W1 = (const float*)d_in[10];
  const float* g2b1 = (const float*)d_in[11];
  const float* g2W2 = (const float*)d_in[12];
  const float* g2b2 = (const float*)d_in[13];
  const float* fW1  = (const float*)d_in[14];
  const float* fb1  = (const float*)d_in[15];
  const float* fW2  = (const float*)d_in[16];
  const float* fb2  = (const float*)d_in[17];

  const int N = in_sizes[0] / 128;
  const int M = in_sizes[1] / 128;
  const int E = in_sizes[4] / 2;
  const int* src = edge;
  const int* dst = edge + E;

  float* ws = (float*)d_ws;
  float* A2   = ws;                          // M*128
  float* M2   = A2 + (size_t)M*128;          // M*128
  float* SUMb = M2 + (size_t)M*128;          // M*128
  float* FP   = SUMb + (size_t)M*128;        // N*128
  int* counts     = (int*)(FP + (size_t)N*128);
  int* row_startp = counts + M;
  int* cursor     = row_startp + M;
  int* blocksum   = cursor + M;              // 512
  uintptr_t rp = (uintptr_t)(blocksum + 512);
  rp = (rp + 15) & ~(uintptr_t)15;
  float4* recs = (float4*)rp;                // E * 16B
  uintptr_t wp = (uintptr_t)(recs + E);
  wp = (wp + 15) & ~(uintptr_t)15;
  unsigned short* Wt = (unsigned short*)wp;  // 8 slabs x 16384
  unsigned short* W_g1A  = Wt + 0*16384;
  unsigned short* W_g1B  = Wt + 1*16384;
  unsigned short* W_g1W2 = Wt + 2*16384;
  unsigned short* W_g2A  = Wt + 3*16384;
  unsigned short* W_g2B  = Wt + 4*16384;
  unsigned short* W_g2W2 = Wt + 5*16384;
  unsigned short* W_fW1  = Wt + 6*16384;
  unsigned short* W_fW2  = Wt + 7*16384;
  float* out = (float*)d_out;

  hipMemsetAsync(counts, 0, (size_t)M*sizeof(int), stream);
  hipMemsetAsync(SUMb, 0, (size_t)M*128*sizeof(float), stream);

  WPtrs p;
  p.s[0] = g1W1;            p.s[1] = g1W1 + 128*128;  p.s[2] = g1W2;
  p.s[3] = g2W1;            p.s[4] = g2W1 + 128*128;  p.s[5] = g2W2;
  p.s[6] = fW1;             p.s[7] = fW2;
  transpose_w8<<<128, 256, 0, stream>>>(p, Wt);

  const int nbMt = (M + 63) / 64;
  const int nbN  = (N + 63) / 64;
  const int nbE  = (E + 255) / 256;
  const int nbS  = (M + 255) / 256;

  prep_mfma<<<dim3(nbMt, 2), 256, 0, stream>>>(res, meta, W_g2A, W_g2B, g2b1,
                                               A2, M2, M);

  hist_kernel<<<nbE, 256, 0, stream>>>(dst, counts, E);
  scan1<<<nbS, 256, 0, stream>>>(counts, row_startp, blocksum, M);
  scan2<<<1, 512, 0, stream>>>(blocksum, nbS);
  scan3<<<nbS, 256, 0, stream>>>(row_startp, blocksum, cursor, M);
  fill_kernel<<<nbE, 256, 0, stream>>>(src, dst, evec, cursor, recs, E);

  const int nEdge = M * S_SPLIT;
  const int gf = ((nEdge + 4) / 5) > nbN ? ((nEdge + 4) / 5) : nbN;
  union_kernel<<<gf*6, 256, 0, stream>>>(A2, M2, meta, recs, row_startp, counts,
                                         g2W1, W_g2W2, g2b2, SUMb, nEdge,
                                         res, sec_ids, pe, g1W1,
                                         W_g1A, W_g1B, W_g1W2, g1b1, g1b2,
                                         FP, N, nbN);

  fnb_kernel<<<nbN, 256, 0, stream>>>(FP, SUMb, counts, M,
                                      W_fW1, fb1, W_fW2, fb2, out, N);
}